// Round 19
// baseline (92.307 us; speedup 1.0000x reference)
//
#include <hip/hip_runtime.h>
#include <hip/hip_bf16.h>

#define SEQ   512
#define LPAD  64
#define RPAD  68
#define TOT   (SEQ + LPAD + RPAD)   // 644 float4 per sequence
#define C1f   14.426950408889634f    // 1/(gamma*ln2), gamma=0.1
#define K1f   0.069314718055994531f  // gamma*ln2

#if __has_builtin(__builtin_amdgcn_exp2f)
#define EXP2(x) __builtin_amdgcn_exp2f(x)
#else
#define EXP2(x) exp2f(x)
#endif

#define SB() __builtin_amdgcn_sched_barrier(0)

__device__ __forceinline__ float cost4(float4 X, float4 Y) {
  return fabsf(X.x - Y.x) + fabsf(X.y - Y.y) + fabsf(X.z - Y.z) + fabsf(X.w - Y.w);
}

// f64 lane shifts via DPP wave shifts: VALU, 0-fill at edges (0 == exp-domain BIG).
__device__ __forceinline__ double dshr1(double x) {  // lane t <- lane t+1; lane63 <- 0
  int lo = __builtin_amdgcn_update_dpp(0, __double2loint(x), 0x138, 0xF, 0xF, true);
  int hi = __builtin_amdgcn_update_dpp(0, __double2hiint(x), 0x138, 0xF, 0xF, true);
  return __hiloint2double(hi, lo);
}
__device__ __forceinline__ double dshl1(double x) {  // lane t <- lane t-1; lane0 <- 0
  int lo = __builtin_amdgcn_update_dpp(0, __double2loint(x), 0x130, 0xF, 0xF, true);
  int hi = __builtin_amdgcn_update_dpp(0, __double2hiint(x), 0x130, 0xF, 0xF, true);
  return __hiloint2double(hi, lo);
}
__device__ __forceinline__ double pow2i(int k) {     // 2^k exactly, |k| <= ~500
  union { unsigned long long u; double d; } v;
  v.u = ((unsigned long long)(1023 + k)) << 52;
  return v.d;
}

// ---- R18 algebra, TWO independent problems (prefix a/b) per wave ----
// 1 cell/lane, band u = t; pair n covers diags 2n+1, 2n+2.
//   odd : diag=dA, left=dB, up=dshl1(dB);  even: diag=dB, up=nA, left=dshr1(nA)
// windows: X0 = x[n+t-31], X1 = x[n+t-30], Y0 = y[n-t+32]
// 6 rotating slots; pair m -> slot m%6. TWO pairs per SB region; servo
// feedback every other region (cadence 4 pairs), bump split across the
// feedback-region's two COMPPs; queue depth 1; clamp +-440.
#define DECLP(p, s) \
  float4 X0##p##s, X1##p##s, Y0##p##s; \
  double Po##p##s, Pe##p##s; \
  int k1##p##s, k2##p##s;

#define LOADW(p, s, m) do { \
    X0##p##s = pX##p[(m)]; X1##p##s = pX##p[(m) + 1]; Y0##p##s = pY##p[(m)]; } while (0)

#define COMPP(p, s, bump) do { \
    k1##p##s = (bump) >> 1; k2##p##s = (bump) - k1##p##s; \
    float _f1 = (float)k1##p##s, _f2 = (float)k2##p##s; \
    Po##p##s = (double)EXP2(fmaf(cost4(X0##p##s, Y0##p##s), -C1f, _f1)); \
    Pe##p##s = (double)EXP2(fmaf(cost4(X1##p##s, Y0##p##s), -C1f, _f2)); } while (0)

#define CHAIN(p, s, sp) do { \
    double _s2p = pow2i(k2##p##sp), _s1c = pow2i(k1##p##s); \
    double _up = dshl1(dB##p); \
    double _nA = Po##p##s * fma(dA##p, _s2p, dB##p + _up); \
    double _lf = dshr1(_nA); \
    double _nB = Pe##p##s * fma(dB##p, _s1c, _nA + _lf); \
    dA##p = _nA; dB##p = _nB; } while (0)

#define FEEDBACK2(p) do { \
    int _hib = __builtin_amdgcn_readlane(__double2hiint(dB##p), 31); \
    int _def = 1023 - ((_hib >> 20) & 0x7ff); \
    Ktot##p += bq1##p; \
    int _nb = _def - bq1##p; _nb = _nb < -440 ? -440 : (_nb > 440 ? 440 : _nb); \
    bq1##p = _nb; } while (0)

// Even group (servo): bump split across the two COMPPs. Both problems.
#define GROUPF(A, B, C, D, E, F, m) do { \
    SB(); \
    LOADW(a, E, (m)); LOADW(a, F, (m) + 1); \
    LOADW(b, E, (m)); LOADW(b, F, (m) + 1); \
    { int _h1 = bq1a >> 1, _h2 = bq1a - _h1; COMPP(a, C, _h1); COMPP(a, D, _h2); } \
    { int _h1 = bq1b >> 1, _h2 = bq1b - _h1; COMPP(b, C, _h1); COMPP(b, D, _h2); } \
    CHAIN(a, A, F); CHAIN(b, A, F); \
    CHAIN(a, B, A); CHAIN(b, B, A); \
    FEEDBACK2(a); FEEDBACK2(b); } while (0)

// Odd group: no bump, no feedback.
#define GROUPN(A, B, C, D, E, F, m) do { \
    SB(); \
    LOADW(a, E, (m)); LOADW(a, F, (m) + 1); \
    LOADW(b, E, (m)); LOADW(b, F, (m) + 1); \
    COMPP(a, C, 0); COMPP(a, D, 0); \
    COMPP(b, C, 0); COMPP(b, D, 0); \
    CHAIN(a, A, F); CHAIN(b, A, F); \
    CHAIN(a, B, A); CHAIN(b, B, A); } while (0)

#define READOUT(p, q) do { \
    if (t == 31) { \
      unsigned long long _bits = __double_as_longlong(dB##p); \
      int _ee = (int)((_bits >> 52) & 0x7ffull); \
      double _mant = __longlong_as_double((_bits & 0xFFFFFFFFFFFFFull) | (1023ull << 52)); \
      double _l2 = (double)(_ee - 1023) + (double)__log2f((float)_mant); \
      ws[q] = (float)(-(double)K1f * (_l2 - (double)Ktot##p)); \
    } } while (0)

// Blocks 0..47: TWO banded soft-DTW problems per block (q = 2blk, 2blk+1).
// Block 48: KL + transition-count losses -> ws[96..98]. Runs concurrently.
__global__ __launch_bounds__(256, 1) void sdtw_fused_kernel(
    const float* __restrict__ at,    // [32,512,4]
    const float* __restrict__ mu,    // [32,64]
    const float* __restrict__ lv,    // [32,64]
    const float* __restrict__ ptc,   // [32,1]
    const float* __restrict__ gt,    // [32,512,4]
    float* __restrict__ ws)          // [0..95]=v, [96]=klS, [97]=auxS, [98]=trS
{
  __shared__ float4 sxA[TOT], syA[TOT], sxB[TOT], syB[TOT];
  __shared__ float s_g[32], s_ps[32], s_kl[32];

  const int blk = blockIdx.x;
  const int t   = threadIdx.x;

  if (blk < 48) {
    const int q0 = 2 * blk, q1 = 2 * blk + 1;
    auto seqs = [&](int q, const float*& xs, const float*& ys) {
      if (q < 32)      { xs = at + (size_t)q        * SEQ * 4; ys = gt + (size_t)q * SEQ * 4; }
      else if (q < 64) { xs = at + (size_t)(q - 32) * SEQ * 4; ys = xs; }
      else             { xs = gt + (size_t)(q - 64) * SEQ * 4; ys = xs; }
    };
    const float *xs0, *ys0, *xs1, *ys1;
    seqs(q0, xs0, ys0);
    seqs(q1, xs1, ys1);

    const float4 zz = make_float4(0.f, 0.f, 0.f, 0.f);
    for (int i = t; i < TOT; i += 256) {
      int j = i - LPAD;
      bool in = (j >= 0) && (j < SEQ);
      int jc = in ? j : 0;
      sxA[i] = in ? ((const float4*)xs0)[jc] : zz;
      syA[i] = in ? ((const float4*)ys0)[jc] : zz;
      sxB[i] = in ? ((const float4*)xs1)[jc] : zz;
      syB[i] = in ? ((const float4*)ys1)[jc] : zz;
    }
    __syncthreads();
    if (t >= 64) return;   // single wave runs both wavefronts; no more barriers

    const float4* sxpa = sxA + LPAD;
    const float4* sypa = syA + LPAD;
    const float4* sxpb = sxB + LPAD;
    const float4* sypb = syB + LPAD;
    const float4* pXa = sxpa + (t - 31);
    const float4* pYa = sypa + (32 - t);
    const float4* pXb = sxpb + (t - 31);
    const float4* pYb = sypb + (32 - t);

    // seeds (pair -1 even diag at lane31; its slot is 5, k2_5 = 0)
    float a0a = -C1f * cost4(sxpa[0], sypa[0]);
    int   n0a = (int)floorf(a0a);
    double dAa = 0.0, dBa = (t == 31) ? (double)EXP2(a0a - (float)n0a) : 0.0;
    int Ktota = -n0a, bq1a = 0;

    float a0b = -C1f * cost4(sxpb[0], sypb[0]);
    int   n0b = (int)floorf(a0b);
    double dAb = 0.0, dBb = (t == 31) ? (double)EXP2(a0b - (float)n0b) : 0.0;
    int Ktotb = -n0b, bq1b = 0;

    DECLP(a, 0) DECLP(a, 1) DECLP(a, 2) DECLP(a, 3) DECLP(a, 4) DECLP(a, 5)
    DECLP(b, 0) DECLP(b, 1) DECLP(b, 2) DECLP(b, 3) DECLP(b, 4) DECLP(b, 5)
    k2a5 = 0; k1a5 = 0; k2b5 = 0; k1b5 = 0;

    // prologue: windows for pairs 0..3; P for pairs 0,1 (bumps 0)
    LOADW(a, 0, 0); LOADW(a, 1, 1); LOADW(a, 2, 2); LOADW(a, 3, 3);
    LOADW(b, 0, 0); LOADW(b, 1, 1); LOADW(b, 2, 2); LOADW(b, 3, 3);
    COMPP(a, 0, 0); COMPP(a, 1, 0);
    COMPP(b, 0, 0); COMPP(b, 1, 0);

    // steady: groups k=0..251 (6 per iter; slot period 3 x feedback period 2)
    #pragma unroll 1
    for (int g = 0; g < 42; ++g) {
      const int m = 12 * g;
      GROUPF(0, 1, 2, 3, 4, 5, m + 4);    // k = 6g
      GROUPN(2, 3, 4, 5, 0, 1, m + 6);    // k = 6g+1
      GROUPF(4, 5, 0, 1, 2, 3, m + 8);    // k = 6g+2
      GROUPN(0, 1, 2, 3, 4, 5, m + 10);   // k = 6g+3
      GROUPF(2, 3, 4, 5, 0, 1, m + 12);   // k = 6g+4
      GROUPN(4, 5, 0, 1, 2, 3, m + 14);   // k = 6g+5
    }
    GROUPF(0, 1, 2, 3, 4, 5, 508);        // k = 252 (chains 504,505)
    GROUPN(2, 3, 4, 5, 0, 1, 510);        // k = 253 (chains 506,507)
    GROUPF(4, 5, 0, 1, 2, 3, 512);        // k = 254 (chains 508,509; COMPP 510)
    // epilogue: pair 510 (slot 0; prev pair 509 in slot 5)
    SB();
    CHAIN(a, 0, 5);
    CHAIN(b, 0, 5);

    READOUT(a, q0);
    READOUT(b, q1);
    return;
  }

  // ---------- loss block (blk == 48), 256 threads: 8 per batch element ----------
  const int b = t >> 3, seg = t & 7;

  float s = 0.f;
  {
    const float* mb = mu + b * 64 + seg * 8;
    const float* lb = lv + b * 64 + seg * 8;
    #pragma unroll
    for (int z = 0; z < 8; ++z) {
      float m = mb[z], l = lb[z];
      s += 1.0f + l - m * m - __expf(l);
    }
  }
  s += __shfl_down(s, 4, 8);
  s += __shfl_down(s, 2, 8);
  s += __shfl_down(s, 1, 8);

  float g = 0.f, ps = 0.f;
  {
    const int n0 = seg * 64;
    const int nstart = (seg == 0) ? 1 : n0;
    const float* gb = gt + (size_t)b * SEQ * 4 + 2;
    const float* ab = at + (size_t)b * SEQ * 4 + 2;
    float pg = gb[(nstart - 1) * 4];
    float pp = 1.0f / (1.0f + __expf((0.5f - ab[(nstart - 1) * 4]) * 10.0f));
    for (int n = nstart; n < n0 + 64; ++n) {
      float cg = gb[n * 4]; g += fabsf(cg - pg); pg = cg;
      float cp = 1.0f / (1.0f + __expf((0.5f - ab[n * 4]) * 10.0f));
      ps += fabsf(cp - pp); pp = cp;
    }
  }
  g  += __shfl_down(g, 4, 8);  g  += __shfl_down(g, 2, 8);  g  += __shfl_down(g, 1, 8);
  ps += __shfl_down(ps, 4, 8); ps += __shfl_down(ps, 2, 8); ps += __shfl_down(ps, 1, 8);

  if (seg == 0) {
    s_g[b]  = g;
    s_ps[b] = ps;
    s_kl[b] = fmaxf(-0.5f * s - 0.5f, 0.0f);
  }
  __syncthreads();

  if (t < 32) {
    float gv  = s_g[t];
    float kl  = s_kl[t];
    float d   = ptc[t] - gv;  float aux = d * d;
    float e   = s_ps[t] - gv; float tr  = e * e;
    kl  += __shfl_down(kl, 16, 32); aux += __shfl_down(aux, 16, 32); tr += __shfl_down(tr, 16, 32);
    kl  += __shfl_down(kl,  8, 32); aux += __shfl_down(aux,  8, 32); tr += __shfl_down(tr,  8, 32);
    kl  += __shfl_down(kl,  4, 32); aux += __shfl_down(aux,  4, 32); tr += __shfl_down(tr,  4, 32);
    kl  += __shfl_down(kl,  2, 32); aux += __shfl_down(aux,  2, 32); tr += __shfl_down(tr,  2, 32);
    kl  += __shfl_down(kl,  1, 32); aux += __shfl_down(aux,  1, 32); tr += __shfl_down(tr,  1, 32);
    if (t == 0) { ws[96] = kl; ws[97] = aux; ws[98] = tr; }
  }
}

__global__ __launch_bounds__(64) void sdtw_combine_kernel(
    const float* __restrict__ ws, float* __restrict__ out)
{
  const int t = threadIdx.x;
  float vn = 0.f;
  if (t < 32) vn = ws[t] - 0.5f * (ws[32 + t] + ws[64 + t]);
  vn += __shfl_down(vn, 16, 32);
  vn += __shfl_down(vn,  8, 32);
  vn += __shfl_down(vn,  4, 32);
  vn += __shfl_down(vn,  2, 32);
  vn += __shfl_down(vn,  1, 32);
  if (t == 0) {
    float recon = vn * (1.0f / 1024.0f);   // mean(diag(v)) = sum/1024
    float kl    = ws[96] * (1.0f / 32.0f);
    float aux   = ws[97] * (1.0f / 32.0f);
    float tr    = ws[98] * (1.0f / 32.0f);
    out[0] = recon + kl + 0.1f * aux + 0.5f * tr;
    out[1] = recon;
    out[2] = kl;
    out[3] = aux;
    out[4] = tr;
  }
}

extern "C" void kernel_launch(void* const* d_in, const int* in_sizes, int n_in,
                              void* d_out, int out_size, void* d_ws, size_t ws_size,
                              hipStream_t stream) {
  const float* at  = (const float*)d_in[0];
  const float* mu  = (const float*)d_in[1];
  const float* lv  = (const float*)d_in[2];
  const float* ptc = (const float*)d_in[3];
  const float* gt  = (const float*)d_in[4];
  float* ws  = (float*)d_ws;
  float* out = (float*)d_out;

  sdtw_fused_kernel<<<49, 256, 0, stream>>>(at, mu, lv, ptc, gt, ws);
  sdtw_combine_kernel<<<1, 64, 0, stream>>>(ws, out);
}

// Round 20
// 48.233 us; speedup vs baseline: 1.9138x; 1.9138x over previous
//
#include <hip/hip_runtime.h>
#include <hip/hip_bf16.h>

#define SEQ   512
#define LPAD  64
#define RPAD  68
#define TOT   (SEQ + LPAD + RPAD)   // 644 float4 per sequence
#define C1f   14.426950408889634f    // 1/(gamma*ln2), gamma=0.1
#define K1f   0.069314718055994531f  // gamma*ln2

#if __has_builtin(__builtin_amdgcn_exp2f)
#define EXP2(x) __builtin_amdgcn_exp2f(x)
#else
#define EXP2(x) exp2f(x)
#endif

#define SB() __builtin_amdgcn_sched_barrier(0)

__device__ __forceinline__ float cost4(float4 X, float4 Y) {
  return fabsf(X.x - Y.x) + fabsf(X.y - Y.y) + fabsf(X.z - Y.z) + fabsf(X.w - Y.w);
}

// f64 lane shifts via DPP wave shifts: VALU, 0-fill at edges (0 == exp-domain BIG).
__device__ __forceinline__ double dshr1(double x) {  // lane t <- lane t+1; lane63 <- 0
  int lo = __builtin_amdgcn_update_dpp(0, __double2loint(x), 0x138, 0xF, 0xF, true);
  int hi = __builtin_amdgcn_update_dpp(0, __double2hiint(x), 0x138, 0xF, 0xF, true);
  return __hiloint2double(hi, lo);
}
__device__ __forceinline__ double dshl1(double x) {  // lane t <- lane t-1; lane0 <- 0
  int lo = __builtin_amdgcn_update_dpp(0, __double2loint(x), 0x130, 0xF, 0xF, true);
  int hi = __builtin_amdgcn_update_dpp(0, __double2hiint(x), 0x130, 0xF, 0xF, true);
  return __hiloint2double(hi, lo);
}
__device__ __forceinline__ double pow2i(int k) {     // 2^k exactly, |k| <= ~500
  union { unsigned long long u; double d; } v;
  v.u = ((unsigned long long)(1023 + k)) << 52;
  return v.d;
}

// ---- 1 cell/lane, band u = t in [0,63]; f64 exp-domain DP (R14 algebra) ----
// pair n covers diags p=2n+1 (odd) and p=2n+2 (even).
//   odd  cell: i = n+t-31, j = n-t+32; neighbors: diag=dA, left=dB, up=dshl1(dB)
//   even cell: i = n+t-30, j = n-t+32; neighbors: diag=dB, up=nA, left=dshr1(nA)
// windows: X0 = x[n+t-31], X1 = x[n+t-30], Y0 = y[n-t+32]
// 6 rotating slots; pair m -> slot m%6. TWO pairs per SB scheduling region.
// Servo feedback runs every OTHER region (once per 4 pairs): the group bump
// is split across the feedback region's two COMPPs; queue depth 1; clamp +-440.
#define DECLS(s) \
  float4 X0##s, X1##s, Y0##s; \
  double Po##s, Pe##s; \
  int k1##s, k2##s;

#define LOADW(s, m) do { \
    X0##s = pX[(m)]; X1##s = pX[(m) + 1]; Y0##s = pY[(m)]; } while (0)

// P factors for the pair in slot s with scale bump folded into the exp2 arg.
#define COMPP(s, bump) do { \
    k1##s = (bump) >> 1; k2##s = (bump) - k1##s; \
    float _f1 = (float)k1##s, _f2 = (float)k2##s; \
    Po##s = (double)EXP2(fmaf(cost4(X0##s, Y0##s), -C1f, _f1)); \
    Pe##s = (double)EXP2(fmaf(cost4(X1##s, Y0##s), -C1f, _f2)); } while (0)

// f64 recurrence for one pair; sp = previous pair's slot (supplies k2prev).
#define CHAIN(s, sp) do { \
    double _s2p = pow2i(k2##sp), _s1c = pow2i(k1##s); \
    double _up = dshl1(dB); \
    double _nA = Po##s * fma(dA, _s2p, dB + _up); \
    double _lf = dshr1(_nA); \
    double _nB = Pe##s * fma(dB, _s1c, _nA + _lf); \
    dA = _nA; dB = _nB; } while (0)

// servo feedback, cadence = every other region. The bump bq1 was consumed by
// THIS region's COMPPs (chains next region -> not yet visible in dB), so
// in-flight = bq1 and the new correction is def - bq1. Ktot counts bq1 here
// (the one place it is applied).
#define FEEDBACK2() do { \
    int _hib = __builtin_amdgcn_readlane(__double2hiint(dB), 31); \
    int _def = 1023 - ((_hib >> 20) & 0x7ff); \
    Ktot += bq1; \
    int _nb = _def - bq1; _nb = _nb < -440 ? -440 : (_nb > 440 ? 440 : _nb); \
    bq1 = _nb; } while (0)

// Even group (with servo): bump split across the two COMPPs.
#define GROUPF(A, B, C, D, E, F, m) do { \
    SB(); \
    LOADW(E, (m));     LOADW(F, (m) + 1); \
    { int _h1 = bq1 >> 1, _h2 = bq1 - _h1; \
      COMPP(C, _h1);   COMPP(D, _h2); } \
    CHAIN(A, F);       CHAIN(B, A); \
    FEEDBACK2(); } while (0)

// Odd group: no bump, no feedback.
#define GROUPN(A, B, C, D, E, F, m) do { \
    SB(); \
    LOADW(E, (m));     LOADW(F, (m) + 1); \
    COMPP(C, 0);       COMPP(D, 0); \
    CHAIN(A, F);       CHAIN(B, A); } while (0)

// Blocks 0..95: banded soft-DTW per extended batch element -> ws[b].
// Block 96: KL + transition-count losses -> ws[96..98]. Runs concurrently.
__global__ __launch_bounds__(256, 1) void sdtw_fused_kernel(
    const float* __restrict__ at,    // [32,512,4]
    const float* __restrict__ mu,    // [32,64]
    const float* __restrict__ lv,    // [32,64]
    const float* __restrict__ ptc,   // [32,1]
    const float* __restrict__ gt,    // [32,512,4]
    float* __restrict__ ws)          // [0..95]=v, [96]=klS, [97]=auxS, [98]=trS
{
  __shared__ float4 sx[TOT];
  __shared__ float4 sy[TOT];
  __shared__ float s_g[32], s_ps[32], s_kl[32];

  const int blk = blockIdx.x;
  const int t   = threadIdx.x;

  if (blk < 96) {
    const float* xs;
    const float* ys;
    if (blk < 32)      { xs = at + (size_t)blk        * SEQ * 4; ys = gt + (size_t)blk * SEQ * 4; }
    else if (blk < 64) { xs = at + (size_t)(blk - 32) * SEQ * 4; ys = xs; }
    else               { xs = gt + (size_t)(blk - 64) * SEQ * 4; ys = xs; }

    for (int i = t; i < LPAD; i += 256) {
      sx[i] = make_float4(0.f, 0.f, 0.f, 0.f);
      sy[i] = make_float4(0.f, 0.f, 0.f, 0.f);
    }
    for (int i = LPAD + SEQ + t; i < TOT; i += 256) {
      sx[i] = make_float4(0.f, 0.f, 0.f, 0.f);
      sy[i] = make_float4(0.f, 0.f, 0.f, 0.f);
    }
    for (int i = t; i < SEQ; i += 256) {
      sx[LPAD + i] = ((const float4*)xs)[i];
      sy[LPAD + i] = ((const float4*)ys)[i];
    }
    __syncthreads();
    if (t >= 64) return;   // single wave runs the wavefront; no more barriers

    const float4* sxp = sx + LPAD;
    const float4* syp = sy + LPAD;
    const float4* pX = sxp + (t - 31);   // pX[m] = x[m+t-31]
    const float4* pY = syp + (32 - t);   // pY[m] = y[m-t+32]

    // seed: diag 0 = (0,0) at lane31 (even diag of pair -1; its slot is 5, k2_5=0)
    float a0 = -C1f * cost4(sxp[0], syp[0]);
    int   n0 = (int)floorf(a0);
    double e00 = (double)EXP2(a0 - (float)n0);
    double dA = 0.0;
    double dB = (t == 31) ? e00 : 0.0;
    int Ktot = -n0;
    int bq1 = 0;

    DECLS(0) DECLS(1) DECLS(2) DECLS(3) DECLS(4) DECLS(5)
    k25 = 0;   // pair -1's even bump (read by CHAIN(0,5) in group 0)
    k15 = 0;

    // prologue: windows for pairs 0..3; P for pairs 0,1 (bumps 0)
    LOADW(0, 0); LOADW(1, 1); LOADW(2, 2); LOADW(3, 3);
    COMPP(0, 0); COMPP(1, 0);

    // steady: groups k=0..251 in the loop (6 groups / iter; slot period 3,
    // feedback period 2 -> combined period 6), then tail groups 252..254.
    #pragma unroll 1
    for (int g = 0; g < 42; ++g) {
      const int m = 12 * g;
      GROUPF(0, 1, 2, 3, 4, 5, m + 4);    // k = 6g
      GROUPN(2, 3, 4, 5, 0, 1, m + 6);    // k = 6g+1
      GROUPF(4, 5, 0, 1, 2, 3, m + 8);    // k = 6g+2
      GROUPN(0, 1, 2, 3, 4, 5, m + 10);   // k = 6g+3
      GROUPF(2, 3, 4, 5, 0, 1, m + 12);   // k = 6g+4
      GROUPN(4, 5, 0, 1, 2, 3, m + 14);   // k = 6g+5
    }
    GROUPF(0, 1, 2, 3, 4, 5, 508);        // k = 252 (chains 504,505)
    GROUPN(2, 3, 4, 5, 0, 1, 510);        // k = 253 (chains 506,507)
    GROUPF(4, 5, 0, 1, 2, 3, 512);        // k = 254 (chains 508,509; COMPP 510)
    // epilogue: pair 510 (slot 0; prev pair 509 in slot 5). Its bump was
    // consumed and Ktot-counted in k=254's GROUPF.
    SB();
    CHAIN(0, 5);

    if (t == 31) {
      // final cell (511,511) = even diag of pair 510, lane31
      // v = -gamma*ln(E_true) = -K1f*(log2(stored) - Ktot)
      unsigned long long bits = __double_as_longlong(dB);
      int ee = (int)((bits >> 52) & 0x7ffull);
      double mant = __longlong_as_double((bits & 0xFFFFFFFFFFFFFull) | (1023ull << 52));
      double l2 = (double)(ee - 1023) + (double)__log2f((float)mant);
      ws[blk] = (float)(-(double)K1f * (l2 - (double)Ktot));
    }
    return;
  }

  // ---------- loss block (blk == 96), 256 threads: 8 per batch element ----------
  const int b = t >> 3, seg = t & 7;

  float s = 0.f;
  {
    const float* mb = mu + b * 64 + seg * 8;
    const float* lb = lv + b * 64 + seg * 8;
    #pragma unroll
    for (int z = 0; z < 8; ++z) {
      float m = mb[z], l = lb[z];
      s += 1.0f + l - m * m - __expf(l);
    }
  }
  s += __shfl_down(s, 4, 8);
  s += __shfl_down(s, 2, 8);
  s += __shfl_down(s, 1, 8);

  float g = 0.f, ps = 0.f;
  {
    const int n0 = seg * 64;
    const int nstart = (seg == 0) ? 1 : n0;
    const float* gb = gt + (size_t)b * SEQ * 4 + 2;
    const float* ab = at + (size_t)b * SEQ * 4 + 2;
    float pg = gb[(nstart - 1) * 4];
    float pp = 1.0f / (1.0f + __expf((0.5f - ab[(nstart - 1) * 4]) * 10.0f));
    for (int n = nstart; n < n0 + 64; ++n) {
      float cg = gb[n * 4]; g += fabsf(cg - pg); pg = cg;
      float cp = 1.0f / (1.0f + __expf((0.5f - ab[n * 4]) * 10.0f));
      ps += fabsf(cp - pp); pp = cp;
    }
  }
  g  += __shfl_down(g, 4, 8);  g  += __shfl_down(g, 2, 8);  g  += __shfl_down(g, 1, 8);
  ps += __shfl_down(ps, 4, 8); ps += __shfl_down(ps, 2, 8); ps += __shfl_down(ps, 1, 8);

  if (seg == 0) {
    s_g[b]  = g;
    s_ps[b] = ps;
    s_kl[b] = fmaxf(-0.5f * s - 0.5f, 0.0f);
  }
  __syncthreads();

  if (t < 32) {
    float gv  = s_g[t];
    float kl  = s_kl[t];
    float d   = ptc[t] - gv;  float aux = d * d;
    float e   = s_ps[t] - gv; float tr  = e * e;
    kl  += __shfl_down(kl, 16, 32); aux += __shfl_down(aux, 16, 32); tr += __shfl_down(tr, 16, 32);
    kl  += __shfl_down(kl,  8, 32); aux += __shfl_down(aux,  8, 32); tr += __shfl_down(tr,  8, 32);
    kl  += __shfl_down(kl,  4, 32); aux += __shfl_down(aux,  4, 32); tr += __shfl_down(tr,  4, 32);
    kl  += __shfl_down(kl,  2, 32); aux += __shfl_down(aux,  2, 32); tr += __shfl_down(tr,  2, 32);
    kl  += __shfl_down(kl,  1, 32); aux += __shfl_down(aux,  1, 32); tr += __shfl_down(tr,  1, 32);
    if (t == 0) { ws[96] = kl; ws[97] = aux; ws[98] = tr; }
  }
}

__global__ __launch_bounds__(64) void sdtw_combine_kernel(
    const float* __restrict__ ws, float* __restrict__ out)
{
  const int t = threadIdx.x;
  float vn = 0.f;
  if (t < 32) vn = ws[t] - 0.5f * (ws[32 + t] + ws[64 + t]);
  vn += __shfl_down(vn, 16, 32);
  vn += __shfl_down(vn,  8, 32);
  vn += __shfl_down(vn,  4, 32);
  vn += __shfl_down(vn,  2, 32);
  vn += __shfl_down(vn,  1, 32);
  if (t == 0) {
    float recon = vn * (1.0f / 1024.0f);   // mean(diag(v)) = sum/1024
    float kl    = ws[96] * (1.0f / 32.0f);
    float aux   = ws[97] * (1.0f / 32.0f);
    float tr    = ws[98] * (1.0f / 32.0f);
    out[0] = recon + kl + 0.1f * aux + 0.5f * tr;
    out[1] = recon;
    out[2] = kl;
    out[3] = aux;
    out[4] = tr;
  }
}

extern "C" void kernel_launch(void* const* d_in, const int* in_sizes, int n_in,
                              void* d_out, int out_size, void* d_ws, size_t ws_size,
                              hipStream_t stream) {
  const float* at  = (const float*)d_in[0];
  const float* mu  = (const float*)d_in[1];
  const float* lv  = (const float*)d_in[2];
  const float* ptc = (const float*)d_in[3];
  const float* gt  = (const float*)d_in[4];
  float* ws  = (float*)d_ws;
  float* out = (float*)d_out;

  sdtw_fused_kernel<<<97, 256, 0, stream>>>(at, mu, lv, ptc, gt, ws);
  sdtw_combine_kernel<<<1, 64, 0, stream>>>(ws, out);
}

// Round 21
// 30.285 us; speedup vs baseline: 3.0479x; 1.5926x over previous
//
#include <hip/hip_runtime.h>
#include <hip/hip_bf16.h>

#define SEQ   512
#define LPAD  64
#define RPAD  68
#define TOT   (SEQ + LPAD + RPAD)   // 644 float4 per sequence
#define C1f   14.426950408889634f    // 1/(gamma*ln2), gamma=0.1
#define K1f   0.069314718055994531f  // gamma*ln2

#if __has_builtin(__builtin_amdgcn_exp2f)
#define EXP2(x) __builtin_amdgcn_exp2f(x)
#else
#define EXP2(x) exp2f(x)
#endif

#define SB() __builtin_amdgcn_sched_barrier(0)

// ws layout (bytes): [0,196608) F/B doubles (96 problems x 256 doubles:
//   [0..63]=F511, [64..127]=F510, [128..191]=B512, [192..255]=B513)
// [196608,198144) scale ints (96 x 4: S510,S511,T512,T513)
// [198144,198528) v floats [96]
// [198528,198540) loss floats klS,auxS,trS
#define OFF_INTS 196608
#define OFF_FV   198144
#define OFF_FLS  198528

__device__ __forceinline__ float cost4(float4 X, float4 Y) {
  return fabsf(X.x - Y.x) + fabsf(X.y - Y.y) + fabsf(X.z - Y.z) + fabsf(X.w - Y.w);
}

// f64 lane shifts via DPP wave shifts: VALU, 0-fill at edges (0 == exp-domain BIG).
__device__ __forceinline__ double dshr1(double x) {  // lane t <- lane t+1; lane63 <- 0
  int lo = __builtin_amdgcn_update_dpp(0, __double2loint(x), 0x138, 0xF, 0xF, true);
  int hi = __builtin_amdgcn_update_dpp(0, __double2hiint(x), 0x138, 0xF, 0xF, true);
  return __hiloint2double(hi, lo);
}
__device__ __forceinline__ double dshl1(double x) {  // lane t <- lane t-1; lane0 <- 0
  int lo = __builtin_amdgcn_update_dpp(0, __double2loint(x), 0x130, 0xF, 0xF, true);
  int hi = __builtin_amdgcn_update_dpp(0, __double2hiint(x), 0x130, 0xF, 0xF, true);
  return __hiloint2double(hi, lo);
}
__device__ __forceinline__ double pow2i(int k) {     // 2^k exactly, |k| <= ~900
  union { unsigned long long u; double d; } v;
  v.u = ((unsigned long long)(1023 + k)) << 52;
  return v.d;
}

// ---- R18 DP core: 1 cell/lane, band u=t, f64 exp-domain, 6 rotating slots,
// 2 pairs per SB region, servo feedback every other region. Each block now
// runs only HALF the chain (255 pairs): fwd = diags 1..510 (+odd step 511),
// bwd = same DP on time-reversed sequences (= orig diags 1021..512).
#define DECLS(s) \
  float4 X0##s, X1##s, Y0##s; \
  double Po##s, Pe##s; \
  int k1##s, k2##s;

#define LOADW(s, m) do { \
    X0##s = pX[(m)]; X1##s = pX[(m) + 1]; Y0##s = pY[(m)]; } while (0)

#define COMPP(s, bump) do { \
    k1##s = (bump) >> 1; k2##s = (bump) - k1##s; \
    float _f1 = (float)k1##s, _f2 = (float)k2##s; \
    Po##s = (double)EXP2(fmaf(cost4(X0##s, Y0##s), -C1f, _f1)); \
    Pe##s = (double)EXP2(fmaf(cost4(X1##s, Y0##s), -C1f, _f2)); } while (0)

#define CHAIN(s, sp) do { \
    double _s2p = pow2i(k2##sp), _s1c = pow2i(k1##s); \
    double _up = dshl1(dB); \
    double _nA = Po##s * fma(dA, _s2p, dB + _up); \
    double _lf = dshr1(_nA); \
    double _nB = Pe##s * fma(dB, _s1c, _nA + _lf); \
    dA = _nA; dB = _nB; } while (0)

#define FEEDBACK2() do { \
    int _hib = __builtin_amdgcn_readlane(__double2hiint(dB), 31); \
    int _def = 1023 - ((_hib >> 20) & 0x7ff); \
    Ktot += bq1; \
    int _nb = _def - bq1; _nb = _nb < -440 ? -440 : (_nb > 440 ? 440 : _nb); \
    bq1 = _nb; } while (0)

#define GROUPF(A, B, C, D, E, F, m) do { \
    SB(); \
    LOADW(E, (m));     LOADW(F, (m) + 1); \
    { int _h1 = bq1 >> 1, _h2 = bq1 - _h1; \
      COMPP(C, _h1);   COMPP(D, _h2); } \
    CHAIN(A, F);       CHAIN(B, A); \
    FEEDBACK2(); } while (0)

#define GROUPN(A, B, C, D, E, F, m) do { \
    SB(); \
    LOADW(E, (m));     LOADW(F, (m) + 1); \
    COMPP(C, 0);       COMPP(D, 0); \
    CHAIN(A, F);       CHAIN(B, A); } while (0)

// Blocks 0..95: fwd half of problem q=blk.  Blocks 96..191: bwd half (reversed
// sequences) of q=blk-96.  Block 192: KL + transition losses.
__global__ __launch_bounds__(256, 1) void sdtw_half_kernel(
    const float* __restrict__ at,    // [32,512,4]
    const float* __restrict__ mu,    // [32,64]
    const float* __restrict__ lv,    // [32,64]
    const float* __restrict__ ptc,   // [32,1]
    const float* __restrict__ gt,    // [32,512,4]
    double* __restrict__ dws,        // F/B diag storage
    int* __restrict__ iws,           // scale ints
    float* __restrict__ fls)         // loss floats [3]
{
  __shared__ float4 sx[TOT];
  __shared__ float4 sy[TOT];
  __shared__ float s_g[32], s_ps[32], s_kl[32];

  const int blk = blockIdx.x;
  const int t   = threadIdx.x;

  if (blk < 192) {
    const bool rev = (blk >= 96);
    const int  q   = rev ? blk - 96 : blk;
    const float* xs;
    const float* ys;
    if (q < 32)      { xs = at + (size_t)q        * SEQ * 4; ys = gt + (size_t)q * SEQ * 4; }
    else if (q < 64) { xs = at + (size_t)(q - 32) * SEQ * 4; ys = xs; }
    else             { xs = gt + (size_t)(q - 64) * SEQ * 4; ys = xs; }

    for (int i = t; i < LPAD; i += 256) {
      sx[i] = make_float4(0.f, 0.f, 0.f, 0.f);
      sy[i] = make_float4(0.f, 0.f, 0.f, 0.f);
    }
    for (int i = LPAD + SEQ + t; i < TOT; i += 256) {
      sx[i] = make_float4(0.f, 0.f, 0.f, 0.f);
      sy[i] = make_float4(0.f, 0.f, 0.f, 0.f);
    }
    for (int i = t; i < SEQ; i += 256) {
      int src = rev ? (SEQ - 1 - i) : i;
      sx[LPAD + i] = ((const float4*)xs)[src];
      sy[LPAD + i] = ((const float4*)ys)[src];
    }
    __syncthreads();
    if (t >= 64) return;   // single wave runs the half-wavefront

    const float4* sxp = sx + LPAD;
    const float4* syp = sy + LPAD;
    const float4* pX = sxp + (t - 31);   // pX[m] = x[m+t-31]
    const float4* pY = syp + (32 - t);   // pY[m] = y[m-t+32]

    // seed: diag 0 = (0,0) at lane31 (even diag of pair -1; slot 5, k2_5 = 0)
    float a0 = -C1f * cost4(sxp[0], syp[0]);
    int   n0 = (int)floorf(a0);
    double e00 = (double)EXP2(a0 - (float)n0);
    double dA = 0.0;
    double dB = (t == 31) ? e00 : 0.0;
    int Ktot = -n0;
    int bq1 = 0;

    DECLS(0) DECLS(1) DECLS(2) DECLS(3) DECLS(4) DECLS(5)
    k25 = 0;   // pair -1's even bump (read by CHAIN(0,5) in group 0)
    k15 = 0;

    // prologue: windows for pairs 0..3; P for pairs 0,1 (bumps 0)
    LOADW(0, 0); LOADW(1, 1); LOADW(2, 2); LOADW(3, 3);
    COMPP(0, 0); COMPP(1, 0);

    // steady: groups k=0..125 (21 iterations x 6), chains pairs 0..251
    #pragma unroll 1
    for (int g = 0; g < 21; ++g) {
      const int m = 12 * g;
      GROUPF(0, 1, 2, 3, 4, 5, m + 4);    // k = 6g
      GROUPN(2, 3, 4, 5, 0, 1, m + 6);    // k = 6g+1
      GROUPF(4, 5, 0, 1, 2, 3, m + 8);    // k = 6g+2
      GROUPN(0, 1, 2, 3, 4, 5, m + 10);   // k = 6g+3
      GROUPF(2, 3, 4, 5, 0, 1, m + 12);   // k = 6g+4
      GROUPN(4, 5, 0, 1, 2, 3, m + 14);   // k = 6g+5
    }
    // k = 126 (even -> GROUPF): chains pairs 252,253; COMPPs pairs 254,255
    GROUPF(0, 1, 2, 3, 4, 5, 256);
    // tail: chain pair 254 (slot 2; prev pair 253 in slot 1)
    SB();
    CHAIN(2, 1);
    // now dA = diag 509, dB = diag 510.
    // Scale accounting: Ktot includes bumps consumed by COMPPs of pairs<=255;
    // dB(510) has pairs<=254 applied -> S510 = Ktot - k13 - k23.
    if (!rev) {
      // fwd-only odd step for pair 255 -> diag 511 (s2p = k2 of pair 254)
      double _s2p = pow2i(k22);
      double _up  = dshl1(dB);
      double f511 = Po3 * fma(dA, _s2p, dB + _up);
      dws[(size_t)q * 256 + t]      = f511;   // diag 511
      dws[(size_t)q * 256 + 64 + t] = dB;     // diag 510
      if (t == 0) {
        iws[q * 4 + 0] = Ktot - k13 - k23;    // S510
        iws[q * 4 + 1] = Ktot - k23;          // S511 = S510 + k1_255
      }
    } else {
      dws[(size_t)q * 256 + 128 + t] = dB;    // B512 (mirrored diag 510)
      dws[(size_t)q * 256 + 192 + t] = dA;    // B513 (mirrored diag 509)
      if (t == 0) {
        int T512 = Ktot - k13 - k23;
        iws[q * 4 + 2] = T512;
        iws[q * 4 + 3] = T512 - k22;          // T513 (dA lags dB by k2_254)
      }
    }
    return;
  }

  // ---------- loss block (blk == 192), 256 threads: 8 per batch element ----------
  const int b = t >> 3, seg = t & 7;

  float s = 0.f;
  {
    const float* mb = mu + b * 64 + seg * 8;
    const float* lb = lv + b * 64 + seg * 8;
    #pragma unroll
    for (int z = 0; z < 8; ++z) {
      float m = mb[z], l = lb[z];
      s += 1.0f + l - m * m - __expf(l);
    }
  }
  s += __shfl_down(s, 4, 8);
  s += __shfl_down(s, 2, 8);
  s += __shfl_down(s, 1, 8);

  float g = 0.f, ps = 0.f;
  {
    const int n0 = seg * 64;
    const int nstart = (seg == 0) ? 1 : n0;
    const float* gb = gt + (size_t)b * SEQ * 4 + 2;
    const float* ab = at + (size_t)b * SEQ * 4 + 2;
    float pg = gb[(nstart - 1) * 4];
    float pp = 1.0f / (1.0f + __expf((0.5f - ab[(nstart - 1) * 4]) * 10.0f));
    for (int n = nstart; n < n0 + 64; ++n) {
      float cg = gb[n * 4]; g += fabsf(cg - pg); pg = cg;
      float cp = 1.0f / (1.0f + __expf((0.5f - ab[n * 4]) * 10.0f));
      ps += fabsf(cp - pp); pp = cp;
    }
  }
  g  += __shfl_down(g, 4, 8);  g  += __shfl_down(g, 2, 8);  g  += __shfl_down(g, 1, 8);
  ps += __shfl_down(ps, 4, 8); ps += __shfl_down(ps, 2, 8); ps += __shfl_down(ps, 1, 8);

  if (seg == 0) {
    s_g[b]  = g;
    s_ps[b] = ps;
    s_kl[b] = fmaxf(-0.5f * s - 0.5f, 0.0f);
  }
  __syncthreads();

  if (t < 32) {
    float gv  = s_g[t];
    float kl  = s_kl[t];
    float d   = ptc[t] - gv;  float aux = d * d;
    float e   = s_ps[t] - gv; float tr  = e * e;
    kl  += __shfl_down(kl, 16, 32); aux += __shfl_down(aux, 16, 32); tr += __shfl_down(tr, 16, 32);
    kl  += __shfl_down(kl,  8, 32); aux += __shfl_down(aux,  8, 32); tr += __shfl_down(tr,  8, 32);
    kl  += __shfl_down(kl,  4, 32); aux += __shfl_down(aux,  4, 32); tr += __shfl_down(tr,  4, 32);
    kl  += __shfl_down(kl,  2, 32); aux += __shfl_down(aux,  2, 32); tr += __shfl_down(tr,  2, 32);
    kl  += __shfl_down(kl,  1, 32); aux += __shfl_down(aux,  1, 32); tr += __shfl_down(tr,  1, 32);
    if (t == 0) { fls[0] = kl; fls[1] = aux; fls[2] = tr; }
  }
}

// Middle combine: every monotone path crosses the diag-511/512 boundary once:
//   E = sum_t F511[t]*(B512[63-t] + B512[62-t] + B513[63-t]*2^(T513-T512))
//     + sum_t F510[t]*B512[62-t]*2^(S510-S511)     (all at ref scale S511+T512)
// Lane mapping derived from fwd cell (224+t, 287-t) and bwd (mirrored) cells.
__global__ __launch_bounds__(64) void sdtw_mid_kernel(
    const double* __restrict__ dws, const int* __restrict__ iws,
    float* __restrict__ fv)
{
  const int b = blockIdx.x, t = threadIdx.x;
  const double* base = dws + (size_t)b * 256;
  double f511 = base[t];
  double f510 = base[64 + t];
  double b512r = base[128 + 63 - t];                    // right succ (diag 512)
  double b512d = (t < 63) ? base[128 + 62 - t] : 0.0;   // down succ (diag 512)
  double b513g = base[192 + 63 - t];                    // diag succ (diag 513)
  int S510 = iws[b * 4], S511 = iws[b * 4 + 1];
  int T512 = iws[b * 4 + 2], T513 = iws[b * 4 + 3];
  double term = f511 * (b512r + b513g * pow2i(T513 - T512))
              + (f511 + f510 * pow2i(S510 - S511)) * b512d;
  term += __shfl_down(term, 32, 64);
  term += __shfl_down(term, 16, 64);
  term += __shfl_down(term,  8, 64);
  term += __shfl_down(term,  4, 64);
  term += __shfl_down(term,  2, 64);
  term += __shfl_down(term,  1, 64);
  if (t == 0) {
    unsigned long long bits = __double_as_longlong(term);
    int ee = (int)((bits >> 52) & 0x7ffull);
    double mant = __longlong_as_double((bits & 0xFFFFFFFFFFFFFull) | (1023ull << 52));
    double l2 = (double)(ee - 1023) + (double)__log2f((float)mant);
    fv[b] = (float)(-(double)K1f * (l2 - (double)(S511 + T512)));
  }
}

__global__ __launch_bounds__(64) void sdtw_final_kernel(
    const float* __restrict__ fv, const float* __restrict__ fls,
    float* __restrict__ out)
{
  const int t = threadIdx.x;
  float vn = 0.f;
  if (t < 32) vn = fv[t] - 0.5f * (fv[32 + t] + fv[64 + t]);
  vn += __shfl_down(vn, 16, 32);
  vn += __shfl_down(vn,  8, 32);
  vn += __shfl_down(vn,  4, 32);
  vn += __shfl_down(vn,  2, 32);
  vn += __shfl_down(vn,  1, 32);
  if (t == 0) {
    float recon = vn * (1.0f / 1024.0f);   // mean(diag(v)) = sum/1024
    float kl    = fls[0] * (1.0f / 32.0f);
    float aux   = fls[1] * (1.0f / 32.0f);
    float tr    = fls[2] * (1.0f / 32.0f);
    out[0] = recon + kl + 0.1f * aux + 0.5f * tr;
    out[1] = recon;
    out[2] = kl;
    out[3] = aux;
    out[4] = tr;
  }
}

extern "C" void kernel_launch(void* const* d_in, const int* in_sizes, int n_in,
                              void* d_out, int out_size, void* d_ws, size_t ws_size,
                              hipStream_t stream) {
  const float* at  = (const float*)d_in[0];
  const float* mu  = (const float*)d_in[1];
  const float* lv  = (const float*)d_in[2];
  const float* ptc = (const float*)d_in[3];
  const float* gt  = (const float*)d_in[4];
  double* dws = (double*)d_ws;
  int*    iws = (int*)((char*)d_ws + OFF_INTS);
  float*  fv  = (float*)((char*)d_ws + OFF_FV);
  float*  fls = (float*)((char*)d_ws + OFF_FLS);
  float*  out = (float*)d_out;

  sdtw_half_kernel<<<193, 256, 0, stream>>>(at, mu, lv, ptc, gt, dws, iws, fls);
  sdtw_mid_kernel<<<96, 64, 0, stream>>>(dws, iws, fv);
  sdtw_final_kernel<<<1, 64, 0, stream>>>(fv, fls, out);
}